// Round 2
// baseline (17740.776 us; speedup 1.0000x reference)
//
#include <hip/hip_runtime.h>
#include <hip/hip_fp16.h>

typedef _Float16 half8 __attribute__((ext_vector_type(8)));
typedef float floatx4 __attribute__((ext_vector_type(4)));

#define H_BYTES  (2ull * 64 * 1024 * 2)     // h double buffer f16 = 256 KB
#define CTL_BYTES 2048ull                   // cnt (1 KB) + flag (1 KB)
#define XP_OFF   (H_BYTES + CTL_BYTES)      // xp AFTER small buffers (OOB -> loud fault)
#define XP_BYTES (512ull * 64 * 1024 * 2)   // x_proj f16 [t][b][dim] = 64 MB

__device__ inline half8 cvt8(const float4 a, const float4 b) {
    half8 r;
    r[0] = (_Float16)a.x; r[1] = (_Float16)a.y; r[2] = (_Float16)a.z; r[3] = (_Float16)a.w;
    r[4] = (_Float16)b.x; r[5] = (_Float16)b.y; r[6] = (_Float16)b.z; r[7] = (_Float16)b.w;
    return r;
}

// ---------------------------------------------------------------------------
// Phase A: x_proj[t][b][n] = sum_k emb[src[b][t]][k] * W_xh[n][k] + b_xh[n]
// 128x128 tile, BK=32, 4 waves in 2x2, f16 MFMA 16x16x32, fp32 accumulate.
// ---------------------------------------------------------------------------
__global__ __launch_bounds__(256) void xproj_kernel(
    const int* __restrict__ src, const float* __restrict__ emb,
    const float* __restrict__ Wxh, const float* __restrict__ bxh,
    _Float16* __restrict__ xp)
{
    __shared__ _Float16 As[128][40];   // +8 pad: 2-way-max bank aliasing
    __shared__ _Float16 Bs[128][40];

    const int tid  = threadIdx.x;
    const int lane = tid & 63;
    const int w    = tid >> 6;
    const int m15  = lane & 15;
    const int quad = lane >> 4;
    const int bid  = blockIdx.x;
    const int bn   = bid & 7;          // 8 column blocks (N=1024)
    const int bm   = bid >> 3;         // 256 row blocks  (M=32768)
    const int m0   = bm * 128, n0 = bn * 128;
    const int wm   = w & 1, wn = w >> 1;

    // staging: 2 threads per row, 16 floats each
    const int  srow = tid >> 1;
    const int  scol = (tid & 1) * 16;
    const long arow = (long)src[m0 + srow] * 1024;   // gather
    const float* abase = emb + arow + scol;
    const float* bbase = Wxh + (long)(n0 + srow) * 1024 + scol;

    floatx4 zero4 = {0.f, 0.f, 0.f, 0.f};
    floatx4 acc[4][4];
#pragma unroll
    for (int mt = 0; mt < 4; mt++)
#pragma unroll
        for (int nt = 0; nt < 4; nt++) acc[mt][nt] = zero4;

    for (int k0 = 0; k0 < 1024; k0 += 32) {
        __syncthreads();   // protect LDS from previous iteration's readers
        float4 a0 = *(const float4*)(abase + k0);
        float4 a1 = *(const float4*)(abase + k0 + 4);
        float4 a2 = *(const float4*)(abase + k0 + 8);
        float4 a3 = *(const float4*)(abase + k0 + 12);
        float4 b0 = *(const float4*)(bbase + k0);
        float4 b1 = *(const float4*)(bbase + k0 + 4);
        float4 b2 = *(const float4*)(bbase + k0 + 8);
        float4 b3 = *(const float4*)(bbase + k0 + 12);
        *(half8*)&As[srow][scol]     = cvt8(a0, a1);
        *(half8*)&As[srow][scol + 8] = cvt8(a2, a3);
        *(half8*)&Bs[srow][scol]     = cvt8(b0, b1);
        *(half8*)&Bs[srow][scol + 8] = cvt8(b2, b3);
        __syncthreads();

        half8 af[4], bf[4];
#pragma unroll
        for (int mt = 0; mt < 4; mt++)
            af[mt] = *(const half8*)&As[wm * 64 + mt * 16 + m15][quad * 8];
#pragma unroll
        for (int nt = 0; nt < 4; nt++)
            bf[nt] = *(const half8*)&Bs[wn * 64 + nt * 16 + m15][quad * 8];
#pragma unroll
        for (int mt = 0; mt < 4; mt++)
#pragma unroll
            for (int nt = 0; nt < 4; nt++)
                acc[mt][nt] = __builtin_amdgcn_mfma_f32_16x16x32_f16(
                    af[mt], bf[nt], acc[mt][nt], 0, 0, 0);
    }

    // epilogue: + bias, store f16 to xp[t][b][n]  (m = b*512 + t)
#pragma unroll
    for (int nt = 0; nt < 4; nt++) {
        const int n = n0 + wn * 64 + nt * 16 + m15;
        const float bias = bxh[n];
#pragma unroll
        for (int mt = 0; mt < 4; mt++) {
            const int mrow = m0 + wm * 64 + mt * 16 + quad * 4;
#pragma unroll
            for (int r = 0; r < 4; r++) {
                const int m = mrow + r;
                const int b = m >> 9;
                const int t = m & 511;
                xp[((long)t * 64 + b) * 1024 + n] = (_Float16)(acc[mt][nt][r] + bias);
            }
        }
    }
}

// ---------------------------------------------------------------------------
// Phase B: persistent recurrence, PLAIN launch (grid=256 <= 256 CUs, each CU
// holds >=1 WG by LDS/VGPR arithmetic => all WGs resident, spin barriers safe;
// coop launch failed silently in R0).
// 256 WGs x 256 thr. group g = wg&15 owns batches [4g,4g+4); member = wg>>4
// owns dims [member*64, member*64+64). Wave w: K-slice [256w,256w+256),
// W_hh slice held in 128 VGPRs (half8 Wf[4][8]) for all 512 steps.
// ---------------------------------------------------------------------------
__global__ __launch_bounds__(256, 1) void rnn_kernel(
    const float* __restrict__ Whh, const _Float16* __restrict__ xp,
    _Float16* __restrict__ hbuf, int* __restrict__ cnt, int* __restrict__ flag,
    float* __restrict__ out)
{
    __shared__ _Float16 hstage[16][1032];       // rows 4..15 stay zero (M-pad)
    __shared__ floatx4  cred[4][4][64];         // [k-slice wave][ntile][lane]

    const int tid    = threadIdx.x;
    const int lane   = tid & 63;
    const int w      = tid >> 6;
    const int m15    = lane & 15;
    const int quad   = lane >> 4;
    const int wg     = blockIdx.x;
    const int g      = wg & 15;
    const int member = wg >> 4;
    const int b0     = g * 4;

    // zero the h staging buffer once (rows 4..15 provide the zero M-padding)
    for (int i = tid; i < 16 * 1032; i += 256) ((_Float16*)hstage)[i] = (_Float16)0.f;

    // load W_hh fragments into registers (f16), reused for all 512 steps
    half8 Wf[4][8];
#pragma unroll
    for (int nt = 0; nt < 4; nt++) {
        const float* wrow = Whh + (long)(member * 64 + nt * 16 + m15) * 1024
                                + w * 256 + quad * 8;
#pragma unroll
        for (int kk = 0; kk < 8; kk++) {
            float4 lo = *(const float4*)(wrow + kk * 32);
            float4 hi = *(const float4*)(wrow + kk * 32 + 4);
            Wf[nt][kk] = cvt8(lo, hi);
        }
    }
    __syncthreads();

    const int dim = member * 64 + w * 16 + m15;   // this lane's output dim (quad 0)
    float xv[4] = {0.f, 0.f, 0.f, 0.f};
    if (quad == 0) {
#pragma unroll
        for (int r = 0; r < 4; r++)
            xv[r] = (float)xp[((long)0 * 64 + b0 + r) * 1024 + dim];
    }

    int* mycnt  = cnt + g * 16;    // 64B-strided per group (no false sharing)
    int* myflag = flag + g * 16;
    floatx4 zero4 = {0.f, 0.f, 0.f, 0.f};

    for (int t = 0; t < 512; t++) {
        const _Float16* hc = hbuf + (size_t)(t & 1) * 65536;
        _Float16*       hn = hbuf + (size_t)((t + 1) & 1) * 65536;

        if (t > 0) {
            if (tid == 0) {
                while (__hip_atomic_load(myflag, __ATOMIC_RELAXED,
                                         __HIP_MEMORY_SCOPE_AGENT) < t) { }
            }
            __syncthreads();
            __threadfence();   // acquire: see other WGs' h stores
        }

        // stage this group's 4 live h rows into LDS (wave w stages row w)
        {
            const int sc = (tid & 63) * 16;
            const _Float16* hrow = hc + (b0 + w) * 1024 + sc;
            uint4 v0 = *(const uint4*)(hrow);
            uint4 v1 = *(const uint4*)(hrow + 8);
            *(uint4*)&hstage[w][sc]     = v0;
            *(uint4*)&hstage[w][sc + 8] = v1;
        }
        __syncthreads();

        // partial GEMM over this wave's K-slice, 4 n-tiles
        floatx4 pacc[4];
#pragma unroll
        for (int nt = 0; nt < 4; nt++) pacc[nt] = zero4;
#pragma unroll
        for (int kk = 0; kk < 8; kk++) {
            half8 a = *(const half8*)&hstage[m15][w * 256 + kk * 32 + quad * 8];
#pragma unroll
            for (int nt = 0; nt < 4; nt++)
                pacc[nt] = __builtin_amdgcn_mfma_f32_16x16x32_f16(
                    a, Wf[nt][kk], pacc[nt], 0, 0, 0);
        }

        // cross-wave K reduction via LDS; wave w finalizes n-tile w
#pragma unroll
        for (int nt = 0; nt < 4; nt++) cred[w][nt][lane] = pacc[nt];
        __syncthreads();
        floatx4 dsum = cred[0][w][lane];
#pragma unroll
        for (int ww = 1; ww < 4; ww++) dsum += cred[ww][w][lane];

        // epilogue: quad 0 holds batches 0..3 in regs 0..3
        if (quad == 0) {
#pragma unroll
            for (int r = 0; r < 4; r++) {
                float pre  = dsum[r] + xv[r];
                float e    = __expf(2.0f * pre);
                float hval = 1.0f - 2.0f / (e + 1.0f);   // tanh
                hn[(b0 + r) * 1024 + dim] = (_Float16)hval;
                if (t == 511) out[(b0 + r) * 1024 + dim] = hval;
            }
        }

        __threadfence();       // release h stores
        __syncthreads();
        if (tid == 0) {
            int old = __hip_atomic_fetch_add(mycnt, 1, __ATOMIC_RELEASE,
                                             __HIP_MEMORY_SCOPE_AGENT);
            if (old == 16 * t + 15)
                __hip_atomic_store(myflag, t + 1, __ATOMIC_RELEASE,
                                   __HIP_MEMORY_SCOPE_AGENT);
        }

        // prefetch x_proj for t+1; drains for free while spinning at next barrier
        if (t < 511 && quad == 0) {
#pragma unroll
            for (int r = 0; r < 4; r++)
                xv[r] = (float)xp[((long)(t + 1) * 64 + b0 + r) * 1024 + dim];
        }
    }
}

extern "C" void kernel_launch(void* const* d_in, const int* in_sizes, int n_in,
                              void* d_out, int out_size, void* d_ws, size_t ws_size,
                              hipStream_t stream) {
    const int*   src = (const int*)d_in[0];
    const float* emb = (const float*)d_in[1];
    const float* Wxh = (const float*)d_in[2];
    const float* bxh = (const float*)d_in[3];
    const float* Whh = (const float*)d_in[4];
    float* out = (float*)d_out;

    char* ws = (char*)d_ws;
    _Float16* hbuf = (_Float16*)ws;
    int* cnt  = (int*)(ws + H_BYTES);
    int* flag = cnt + 256;
    _Float16* xp   = (_Float16*)(ws + XP_OFF);

    // zero h[0] (f16 zeros are bit-zero) and barrier counters/flags
    hipMemsetAsync(ws, 0, H_BYTES + CTL_BYTES, stream);

    hipLaunchKernelGGL(xproj_kernel, dim3(2048), dim3(256), 0, stream,
                       src, emb, Wxh, bxh, xp);

    hipLaunchKernelGGL(rnn_kernel, dim3(256), dim3(256), 0, stream,
                       Whh, xp, hbuf, cnt, flag, out);
}

// Round 3
// 6152.855 us; speedup vs baseline: 2.8833x; 2.8833x over previous
//
#include <hip/hip_runtime.h>
#include <hip/hip_fp16.h>

typedef _Float16 half8 __attribute__((ext_vector_type(8)));
typedef float floatx4 __attribute__((ext_vector_type(4)));

#define H_BYTES   (2ull * 64 * 1024 * 2)    // h double buffer f16 = 256 KB
#define CTL_BYTES (32ull * 1024)            // per-member flag words (16g x 16m x 64B = 16 KB used)
#define XP_OFF    (H_BYTES + CTL_BYTES)
#define XP_BYTES  (512ull * 64 * 1024 * 2)  // x_proj f16 [t][b][dim] = 64 MB
#define FLAG_STRIDE 16                      // ints -> 64 B per member flag

__device__ inline half8 cvt8(const float4 a, const float4 b) {
    half8 r;
    r[0] = (_Float16)a.x; r[1] = (_Float16)a.y; r[2] = (_Float16)a.z; r[3] = (_Float16)a.w;
    r[4] = (_Float16)b.x; r[5] = (_Float16)b.y; r[6] = (_Float16)b.z; r[7] = (_Float16)b.w;
    return r;
}

// ---------------------------------------------------------------------------
// Phase A: x_proj[t][b][n] = sum_k emb[src[b][t]][k] * W_xh[n][k] + b_xh[n]
// 128x128 tile, BK=32, 4 waves in 2x2, f16 MFMA 16x16x32, fp32 accumulate.
// (unchanged from R1 — measured ~300 us, not the bottleneck)
// ---------------------------------------------------------------------------
__global__ __launch_bounds__(256) void xproj_kernel(
    const int* __restrict__ src, const float* __restrict__ emb,
    const float* __restrict__ Wxh, const float* __restrict__ bxh,
    _Float16* __restrict__ xp)
{
    __shared__ _Float16 As[128][40];
    __shared__ _Float16 Bs[128][40];

    const int tid  = threadIdx.x;
    const int lane = tid & 63;
    const int w    = tid >> 6;
    const int m15  = lane & 15;
    const int quad = lane >> 4;
    const int bid  = blockIdx.x;
    const int bn   = bid & 7;
    const int bm   = bid >> 3;
    const int m0   = bm * 128, n0 = bn * 128;
    const int wm   = w & 1, wn = w >> 1;

    const int  srow = tid >> 1;
    const int  scol = (tid & 1) * 16;
    const long arow = (long)src[m0 + srow] * 1024;
    const float* abase = emb + arow + scol;
    const float* bbase = Wxh + (long)(n0 + srow) * 1024 + scol;

    floatx4 zero4 = {0.f, 0.f, 0.f, 0.f};
    floatx4 acc[4][4];
#pragma unroll
    for (int mt = 0; mt < 4; mt++)
#pragma unroll
        for (int nt = 0; nt < 4; nt++) acc[mt][nt] = zero4;

    for (int k0 = 0; k0 < 1024; k0 += 32) {
        __syncthreads();
        float4 a0 = *(const float4*)(abase + k0);
        float4 a1 = *(const float4*)(abase + k0 + 4);
        float4 a2 = *(const float4*)(abase + k0 + 8);
        float4 a3 = *(const float4*)(abase + k0 + 12);
        float4 b0 = *(const float4*)(bbase + k0);
        float4 b1 = *(const float4*)(bbase + k0 + 4);
        float4 b2 = *(const float4*)(bbase + k0 + 8);
        float4 b3 = *(const float4*)(bbase + k0 + 12);
        *(half8*)&As[srow][scol]     = cvt8(a0, a1);
        *(half8*)&As[srow][scol + 8] = cvt8(a2, a3);
        *(half8*)&Bs[srow][scol]     = cvt8(b0, b1);
        *(half8*)&Bs[srow][scol + 8] = cvt8(b2, b3);
        __syncthreads();

        half8 af[4], bf[4];
#pragma unroll
        for (int mt = 0; mt < 4; mt++)
            af[mt] = *(const half8*)&As[wm * 64 + mt * 16 + m15][quad * 8];
#pragma unroll
        for (int nt = 0; nt < 4; nt++)
            bf[nt] = *(const half8*)&Bs[wn * 64 + nt * 16 + m15][quad * 8];
#pragma unroll
        for (int mt = 0; mt < 4; mt++)
#pragma unroll
            for (int nt = 0; nt < 4; nt++)
                acc[mt][nt] = __builtin_amdgcn_mfma_f32_16x16x32_f16(
                    af[mt], bf[nt], acc[mt][nt], 0, 0, 0);
    }

#pragma unroll
    for (int nt = 0; nt < 4; nt++) {
        const int n = n0 + wn * 64 + nt * 16 + m15;
        const float bias = bxh[n];
#pragma unroll
        for (int mt = 0; mt < 4; mt++) {
            const int mrow = m0 + wm * 64 + mt * 16 + quad * 4;
#pragma unroll
            for (int r = 0; r < 4; r++) {
                const int m = mrow + r;
                const int b = m >> 9;
                const int t = m & 511;
                xp[((long)t * 64 + b) * 1024 + n] = (_Float16)(acc[mt][nt][r] + bias);
            }
        }
    }
}

// ---------------------------------------------------------------------------
// Phase B: persistent recurrence, plain launch (256 WGs, 1/CU guaranteed).
// NEW SYNC (R2): zero atomic RMWs. Each (group,member) owns a 64B flag word.
//   producer: plain h stores -> __syncthreads (vmcnt drain) -> release store flag=t+1
//   consumer: lanes 0..15 of wave 0 poll all 16 member flags IN PARALLEL
//             (one global_load per round), then all threads acquire-fence.
// Replaces 16 serialized far-point RMWs/step (~34us measured in R1) with
// ~2-3 far-point latencies/step.
// ---------------------------------------------------------------------------
__global__ __launch_bounds__(256, 1) void rnn_kernel(
    const float* __restrict__ Whh, const _Float16* __restrict__ xp,
    _Float16* __restrict__ hbuf, int* __restrict__ flags,
    float* __restrict__ out)
{
    __shared__ _Float16 hstage[16][1032];       // rows 4..15 stay zero (M-pad)
    __shared__ floatx4  cred[4][4][64];         // [k-slice wave][ntile][lane]

    const int tid    = threadIdx.x;
    const int lane   = tid & 63;
    const int w      = tid >> 6;
    const int m15    = lane & 15;
    const int quad   = lane >> 4;
    const int wg     = blockIdx.x;
    const int g      = wg & 15;
    const int member = wg >> 4;
    const int b0     = g * 4;

    for (int i = tid; i < 16 * 1032; i += 256) ((_Float16*)hstage)[i] = (_Float16)0.f;

    // W_hh slice -> 128 VGPRs (f16), reused for all 512 steps
    half8 Wf[4][8];
#pragma unroll
    for (int nt = 0; nt < 4; nt++) {
        const float* wrow = Whh + (long)(member * 64 + nt * 16 + m15) * 1024
                                + w * 256 + quad * 8;
#pragma unroll
        for (int kk = 0; kk < 8; kk++) {
            float4 lo = *(const float4*)(wrow + kk * 32);
            float4 hi = *(const float4*)(wrow + kk * 32 + 4);
            Wf[nt][kk] = cvt8(lo, hi);
        }
    }
    __syncthreads();

    const int dim = member * 64 + w * 16 + m15;
    float xv[4] = {0.f, 0.f, 0.f, 0.f};
    if (quad == 0) {
#pragma unroll
        for (int r = 0; r < 4; r++)
            xv[r] = (float)xp[((long)0 * 64 + b0 + r) * 1024 + dim];
    }

    int* myflag = flags + (g * 16 + member) * FLAG_STRIDE;
    const int* gflags = flags + g * 16 * FLAG_STRIDE;
    floatx4 zero4 = {0.f, 0.f, 0.f, 0.f};

    for (int t = 0; t < 512; t++) {
        const _Float16* hc = hbuf + (size_t)(t & 1) * 65536;
        _Float16*       hn = hbuf + (size_t)((t + 1) & 1) * 65536;

        if (t > 0) {
            // parallel poll: lane m watches member m's flag; lanes retire
            // individually as their flag lands (exec-mask shrink).
            if (tid < 16) {
                const int* fw = gflags + tid * FLAG_STRIDE;
                while (__hip_atomic_load(fw, __ATOMIC_RELAXED,
                                         __HIP_MEMORY_SCOPE_AGENT) < t) { }
            }
            __syncthreads();
            __builtin_amdgcn_fence(__ATOMIC_ACQUIRE, "agent"); // inv L1/L2: fresh h
        }

        // stage this group's 4 live h rows into LDS (wave w stages row w)
        {
            const int sc = (tid & 63) * 16;
            const _Float16* hrow = hc + (b0 + w) * 1024 + sc;
            uint4 v0 = *(const uint4*)(hrow);
            uint4 v1 = *(const uint4*)(hrow + 8);
            *(uint4*)&hstage[w][sc]     = v0;
            *(uint4*)&hstage[w][sc + 8] = v1;
        }
        __syncthreads();

        // partial GEMM over this wave's K-slice, 4 n-tiles
        floatx4 pacc[4];
#pragma unroll
        for (int nt = 0; nt < 4; nt++) pacc[nt] = zero4;
#pragma unroll
        for (int kk = 0; kk < 8; kk++) {
            half8 a = *(const half8*)&hstage[m15][w * 256 + kk * 32 + quad * 8];
#pragma unroll
            for (int nt = 0; nt < 4; nt++)
                pacc[nt] = __builtin_amdgcn_mfma_f32_16x16x32_f16(
                    a, Wf[nt][kk], pacc[nt], 0, 0, 0);
        }

        // cross-wave K reduction via LDS; wave w finalizes n-tile w
#pragma unroll
        for (int nt = 0; nt < 4; nt++) cred[w][nt][lane] = pacc[nt];
        __syncthreads();
        floatx4 dsum = cred[0][w][lane];
#pragma unroll
        for (int ww = 1; ww < 4; ww++) dsum += cred[ww][w][lane];

        // epilogue: quad 0 holds batches 0..3 in regs 0..3
        if (quad == 0) {
#pragma unroll
            for (int r = 0; r < 4; r++) {
                float pre  = dsum[r] + xv[r];
                float e    = __expf(2.0f * pre);
                float hval = 1.0f - 2.0f / (e + 1.0f);   // tanh
                hn[(b0 + r) * 1024 + dim] = (_Float16)hval;
                if (t == 511) out[(b0 + r) * 1024 + dim] = hval;
            }
        }

        // publish: __syncthreads drains vmcnt(0) for ALL waves' h stores,
        // then one release store (emits L2 writeback) flips our flag.
        __syncthreads();
        if (tid == 0)
            __hip_atomic_store(myflag, t + 1, __ATOMIC_RELEASE,
                               __HIP_MEMORY_SCOPE_AGENT);

        // prefetch x_proj for t+1; drains while spinning at next barrier
        if (t < 511 && quad == 0) {
#pragma unroll
            for (int r = 0; r < 4; r++)
                xv[r] = (float)xp[((long)(t + 1) * 64 + b0 + r) * 1024 + dim];
        }
    }
}

extern "C" void kernel_launch(void* const* d_in, const int* in_sizes, int n_in,
                              void* d_out, int out_size, void* d_ws, size_t ws_size,
                              hipStream_t stream) {
    const int*   src = (const int*)d_in[0];
    const float* emb = (const float*)d_in[1];
    const float* Wxh = (const float*)d_in[2];
    const float* bxh = (const float*)d_in[3];
    const float* Whh = (const float*)d_in[4];
    float* out = (float*)d_out;

    char* ws = (char*)d_ws;
    _Float16* hbuf = (_Float16*)ws;
    int* flags = (int*)(ws + H_BYTES);
    _Float16* xp = (_Float16*)(ws + XP_OFF);

    // zero h[0] (f16 zeros are bit-zero) and flag words
    hipMemsetAsync(ws, 0, H_BYTES + CTL_BYTES, stream);

    hipLaunchKernelGGL(xproj_kernel, dim3(2048), dim3(256), 0, stream,
                       src, emb, Wxh, bxh, xp);

    hipLaunchKernelGGL(rnn_kernel, dim3(256), dim3(256), 0, stream,
                       Whh, xp, hbuf, flags, out);
}

// Round 4
// 1313.453 us; speedup vs baseline: 13.5070x; 4.6845x over previous
//
#include <hip/hip_runtime.h>
#include <hip/hip_fp16.h>

typedef _Float16 half8 __attribute__((ext_vector_type(8)));
typedef float floatx4 __attribute__((ext_vector_type(4)));

// workspace layout
#define HBUF_BYTES (2ull * 16 * 1024 * 8)   // [parity][group][dim] ulong (4 f16 batches) = 256 KB
#define CTL_BYTES  (32ull * 1024)           // flag words, 64 B each
#define XP_OFF     (HBUF_BYTES + CTL_BYTES)
#define XP_BYTES   (512ull * 64 * 1024 * 2) // x_proj f16 [t][b][dim] = 64 MB
#define FLAG_STRIDE 16                      // ints -> 64 B per member flag

union pack4 { unsigned long long u; _Float16 h[4]; };

__device__ inline half8 cvt8(const float4 a, const float4 b) {
    half8 r;
    r[0] = (_Float16)a.x; r[1] = (_Float16)a.y; r[2] = (_Float16)a.z; r[3] = (_Float16)a.w;
    r[4] = (_Float16)b.x; r[5] = (_Float16)b.y; r[6] = (_Float16)b.z; r[7] = (_Float16)b.w;
    return r;
}

// ---------------------------------------------------------------------------
// Phase A: x_proj[t][b][n] = sum_k emb[src[b][t]][k] * W_xh[n][k] + b_xh[n]
// (unchanged — not the bottleneck)
// ---------------------------------------------------------------------------
__global__ __launch_bounds__(256) void xproj_kernel(
    const int* __restrict__ src, const float* __restrict__ emb,
    const float* __restrict__ Wxh, const float* __restrict__ bxh,
    _Float16* __restrict__ xp)
{
    __shared__ _Float16 As[128][40];
    __shared__ _Float16 Bs[128][40];

    const int tid  = threadIdx.x;
    const int lane = tid & 63;
    const int w    = tid >> 6;
    const int m15  = lane & 15;
    const int quad = lane >> 4;
    const int bid  = blockIdx.x;
    const int bn   = bid & 7;
    const int bm   = bid >> 3;
    const int m0   = bm * 128, n0 = bn * 128;
    const int wm   = w & 1, wn = w >> 1;

    const int  srow = tid >> 1;
    const int  scol = (tid & 1) * 16;
    const long arow = (long)src[m0 + srow] * 1024;
    const float* abase = emb + arow + scol;
    const float* bbase = Wxh + (long)(n0 + srow) * 1024 + scol;

    floatx4 zero4 = {0.f, 0.f, 0.f, 0.f};
    floatx4 acc[4][4];
#pragma unroll
    for (int mt = 0; mt < 4; mt++)
#pragma unroll
        for (int nt = 0; nt < 4; nt++) acc[mt][nt] = zero4;

    for (int k0 = 0; k0 < 1024; k0 += 32) {
        __syncthreads();
        float4 a0 = *(const float4*)(abase + k0);
        float4 a1 = *(const float4*)(abase + k0 + 4);
        float4 a2 = *(const float4*)(abase + k0 + 8);
        float4 a3 = *(const float4*)(abase + k0 + 12);
        float4 b0 = *(const float4*)(bbase + k0);
        float4 b1 = *(const float4*)(bbase + k0 + 4);
        float4 b2 = *(const float4*)(bbase + k0 + 8);
        float4 b3 = *(const float4*)(bbase + k0 + 12);
        *(half8*)&As[srow][scol]     = cvt8(a0, a1);
        *(half8*)&As[srow][scol + 8] = cvt8(a2, a3);
        *(half8*)&Bs[srow][scol]     = cvt8(b0, b1);
        *(half8*)&Bs[srow][scol + 8] = cvt8(b2, b3);
        __syncthreads();

        half8 af[4], bf[4];
#pragma unroll
        for (int mt = 0; mt < 4; mt++)
            af[mt] = *(const half8*)&As[wm * 64 + mt * 16 + m15][quad * 8];
#pragma unroll
        for (int nt = 0; nt < 4; nt++)
            bf[nt] = *(const half8*)&Bs[wn * 64 + nt * 16 + m15][quad * 8];
#pragma unroll
        for (int mt = 0; mt < 4; mt++)
#pragma unroll
            for (int nt = 0; nt < 4; nt++)
                acc[mt][nt] = __builtin_amdgcn_mfma_f32_16x16x32_f16(
                    af[mt], bf[nt], acc[mt][nt], 0, 0, 0);
    }

#pragma unroll
    for (int nt = 0; nt < 4; nt++) {
        const int n = n0 + wn * 64 + nt * 16 + m15;
        const float bias = bxh[n];
#pragma unroll
        for (int mt = 0; mt < 4; mt++) {
            const int mrow = m0 + wm * 64 + mt * 16 + quad * 4;
#pragma unroll
            for (int r = 0; r < 4; r++) {
                const int m = mrow + r;
                const int b = m >> 9;
                const int t = m & 511;
                xp[((long)t * 64 + b) * 1024 + n] = (_Float16)(acc[mt][nt][r] + bias);
            }
        }
    }
}

// ---------------------------------------------------------------------------
// Phase B: persistent recurrence, plain launch (256 WGs, 1/CU guaranteed).
// R4 SYNC: NO fences at all. h exchanged as 8-byte relaxed agent atomics
// ([parity][group][dim] ulong, 4 batches packed per dim) — device-coherent
// word ops, no whole-L2 writeback/invalidate. Ordering:
//   producer: atomic h stores -> __syncthreads (vmcnt(0) drain per wave)
//             -> tid0 relaxed flag store
//   consumer: parallel flag poll -> __syncthreads -> relaxed atomic h loads
// ---------------------------------------------------------------------------
__global__ __launch_bounds__(256, 1) void rnn_kernel(
    const float* __restrict__ Whh, const _Float16* __restrict__ xp,
    unsigned long long* __restrict__ hb, int* __restrict__ flags,
    float* __restrict__ out)
{
    __shared__ _Float16 hstage[16][1032];       // rows 4..15 stay zero (M-pad)
    __shared__ floatx4  cred[4][4][64];         // [k-slice wave][ntile][lane]

    const int tid    = threadIdx.x;
    const int lane   = tid & 63;
    const int w      = tid >> 6;
    const int m15    = lane & 15;
    const int quad   = lane >> 4;
    const int wg     = blockIdx.x;
    const int g      = wg & 15;
    const int member = wg >> 4;
    const int b0     = g * 4;

    for (int i = tid; i < 16 * 1032; i += 256) ((_Float16*)hstage)[i] = (_Float16)0.f;

    // W_hh slice -> 128 VGPRs (f16), reused for all 512 steps
    half8 Wf[4][8];
#pragma unroll
    for (int nt = 0; nt < 4; nt++) {
        const float* wrow = Whh + (long)(member * 64 + nt * 16 + m15) * 1024
                                + w * 256 + quad * 8;
#pragma unroll
        for (int kk = 0; kk < 8; kk++) {
            float4 lo = *(const float4*)(wrow + kk * 32);
            float4 hi = *(const float4*)(wrow + kk * 32 + 4);
            Wf[nt][kk] = cvt8(lo, hi);
        }
    }
    __syncthreads();

    const int dim = member * 64 + w * 16 + m15;
    float xv[4] = {0.f, 0.f, 0.f, 0.f};
    if (quad == 0) {
#pragma unroll
        for (int r = 0; r < 4; r++)
            xv[r] = (float)xp[((long)0 * 64 + b0 + r) * 1024 + dim];
    }

    int* myflag = flags + (g * 16 + member) * FLAG_STRIDE;
    const int* gflags = flags + g * 16 * FLAG_STRIDE;
    floatx4 zero4 = {0.f, 0.f, 0.f, 0.f};

    for (int t = 0; t < 512; t++) {
        const unsigned long long* hcu = hb + (size_t)(t & 1) * 16384 + (size_t)g * 1024;
        unsigned long long*       hnu = hb + (size_t)((t + 1) & 1) * 16384 + (size_t)g * 1024;

        if (t > 0) {
            // parallel poll: lane m watches member m's flag
            if (tid < 16) {
                const int* fw = gflags + tid * FLAG_STRIDE;
                while (__hip_atomic_load(fw, __ATOMIC_RELAXED,
                                         __HIP_MEMORY_SCOPE_AGENT) < t) { }
            }
            __syncthreads();
            // NO acquire fence: h loads below are coherent atomic loads.
        }

        // gather h_t (all 1024 dims, 4 batches packed per ulong), transpose to LDS
        {
            unsigned long long v[4];
#pragma unroll
            for (int i = 0; i < 4; i++)
                v[i] = __hip_atomic_load(hcu + tid + 256 * i, __ATOMIC_RELAXED,
                                         __HIP_MEMORY_SCOPE_AGENT);
#pragma unroll
            for (int i = 0; i < 4; i++) {
                pack4 p; p.u = v[i];
                const int d = tid + 256 * i;
#pragma unroll
                for (int b = 0; b < 4; b++) hstage[b][d] = p.h[b];
            }
        }
        __syncthreads();

        // partial GEMM over this wave's K-slice, 4 n-tiles
        floatx4 pacc[4];
#pragma unroll
        for (int nt = 0; nt < 4; nt++) pacc[nt] = zero4;
#pragma unroll
        for (int kk = 0; kk < 8; kk++) {
            half8 a = *(const half8*)&hstage[m15][w * 256 + kk * 32 + quad * 8];
#pragma unroll
            for (int nt = 0; nt < 4; nt++)
                pacc[nt] = __builtin_amdgcn_mfma_f32_16x16x32_f16(
                    a, Wf[nt][kk], pacc[nt], 0, 0, 0);
        }

        // cross-wave K reduction via LDS; wave w finalizes n-tile w
#pragma unroll
        for (int nt = 0; nt < 4; nt++) cred[w][nt][lane] = pacc[nt];
        __syncthreads();
        floatx4 dsum = cred[0][w][lane];
#pragma unroll
        for (int ww = 1; ww < 4; ww++) dsum += cred[ww][w][lane];

        // epilogue: quad 0 holds batches 0..3; pack + one 8B atomic store
        if (quad == 0) {
            pack4 p;
#pragma unroll
            for (int r = 0; r < 4; r++) {
                float pre  = dsum[r] + xv[r];
                float e    = __expf(2.0f * pre);
                float hval = 1.0f - 2.0f / (e + 1.0f);   // tanh
                p.h[r] = (_Float16)hval;
                if (t == 511) out[(b0 + r) * 1024 + dim] = hval;
            }
            __hip_atomic_store(hnu + dim, p.u, __ATOMIC_RELAXED,
                               __HIP_MEMORY_SCOPE_AGENT);
        }

        // publish: barrier drains every wave's vmcnt(0) -> h stores acked,
        // then one relaxed flag store.
        __syncthreads();
        if (tid == 0)
            __hip_atomic_store(myflag, t + 1, __ATOMIC_RELAXED,
                               __HIP_MEMORY_SCOPE_AGENT);

        // prefetch x_proj for t+1; drains while spinning at next barrier
        if (t < 511 && quad == 0) {
#pragma unroll
            for (int r = 0; r < 4; r++)
                xv[r] = (float)xp[((long)(t + 1) * 64 + b0 + r) * 1024 + dim];
        }
    }
}

extern "C" void kernel_launch(void* const* d_in, const int* in_sizes, int n_in,
                              void* d_out, int out_size, void* d_ws, size_t ws_size,
                              hipStream_t stream) {
    const int*   src = (const int*)d_in[0];
    const float* emb = (const float*)d_in[1];
    const float* Wxh = (const float*)d_in[2];
    const float* bxh = (const float*)d_in[3];
    const float* Whh = (const float*)d_in[4];
    float* out = (float*)d_out;

    char* ws = (char*)d_ws;
    unsigned long long* hb = (unsigned long long*)ws;
    int* flags = (int*)(ws + HBUF_BYTES);
    _Float16* xp = (_Float16*)(ws + XP_OFF);

    // zero h[0] (f16 zeros are bit-zero) and flag words
    hipMemsetAsync(ws, 0, HBUF_BYTES + CTL_BYTES, stream);

    hipLaunchKernelGGL(xproj_kernel, dim3(2048), dim3(256), 0, stream,
                       src, emb, Wxh, bxh, xp);

    hipLaunchKernelGGL(rnn_kernel, dim3(256), dim3(256), 0, stream,
                       Whh, xp, hb, flags, out);
}